// Round 21
// baseline (232.686 us; speedup 1.0000x reference)
//
#include <hip/hip_runtime.h>
#include <stdint.h>

// MultiHeadAttention: x[4,2048,1024] fp32; Wq/Wk/Wv/Wo [1024,1024]; biases zero.
// out = softmax((xWq^T)(xWk^T)^T / 32) (xWv^T) Wo^T + bo   (16 heads, d=64)
//
// Pipeline (bf16 MFMA, fp32 accum):
//  k_cvt_all: x,W* fp32->bf16 (single fused launch)
//  k_gemm3/k_gemmo: 128x128 tile, 4 waves (2x2, 64x64/wave), BK=64,
//     global_load_lds staging, 2 barriers/tile — r21: inner math switched
//     16x16x32 -> 32x32x16 MFMA (m119: +15-20% matrix-pipe FLOP/cyc, 4x
//     fewer MFMA issues, half the frag loads). D layout row=(reg&3)+
//     8*(reg>>2)+4*hi, col=l31 — the exact map verified in k_attn (r10+).
//     XCD-partitioned grid. V stored [bh][d][kv], kv PRE-PERMUTED per
//     16-token window (groups {0,1,2,3}->{0,2,1,3}); Q pre-scaled log2e/32.
//  k_attn: 32x32x16 MFMA flash attention, fully in-register softmax (r18
//     structure, unchanged): GLDS K,V -> barrier -> S -> exp/pack -> PV ->
//     barrier; exp+pack = ONE asm block (16 v_exp, s_nop, 8 cvt_pk —
//     TRANS->VALU spacing by construction); den via mfma(P, ones).

#define HID 1024
#define NH 16
#define HD 64
#define BB 4
#define SEQ 2048
#define MTOT (BB * SEQ) // 8192

typedef short bf16x8 __attribute__((ext_vector_type(8)));
typedef float f32x16 __attribute__((ext_vector_type(16)));

// swizzle: byte col within a 128B row, XORed by row&7 (16B granular)
#define SWZ(row, cb) ((cb) ^ (((row) & 7) << 4))

#define GLDS(gp, lp) __builtin_amdgcn_global_load_lds( \
    (const __attribute__((address_space(1))) void*)(gp), \
    (__attribute__((address_space(3))) void*)(lp), 16, 0, 0)

// f32 -> bf16 RNE, manual bit-twiddle (proven; (__bf16) cast failed in r12)
static __device__ __forceinline__ unsigned short f2bf(float f) {
  unsigned u = __float_as_uint(f);
  u += 0x7fffu + ((u >> 16) & 1u); // RNE
  return (unsigned short)(u >> 16);
}

static __device__ __forceinline__ f32x16 mfma32(bf16x8 a, bf16x8 b, f32x16 c) {
  return __builtin_amdgcn_mfma_f32_32x32x16_bf16(a, b, c, 0, 0, 0);
}

// ---------------- fp32 -> bf16 convert, all tensors, one launch ----------------
__global__ void k_cvt_all(const float* __restrict__ x,
                          const float* __restrict__ Wq, const float* __restrict__ Wk,
                          const float* __restrict__ Wv, const float* __restrict__ Wo,
                          unsigned short* __restrict__ ws) {
  const int X4 = MTOT * HID / 4;
  const int W4 = HID * HID / 4;
  int i = blockIdx.x * blockDim.x + threadIdx.x;
  const float* src;
  unsigned short* dst;
  int off;
  if (i < X4) {
    src = x; dst = ws; off = i;
  } else {
    int j = i - X4;
    int w = j / W4;
    off = j - w * W4;
    src = (w == 0) ? Wq : (w == 1) ? Wk : (w == 2) ? Wv : Wo;
    dst = ws + (size_t)MTOT * HID + (size_t)w * HID * HID;
  }
  float4 v = reinterpret_cast<const float4*>(src)[off];
  ushort4 o;
  o.x = f2bf(v.x); o.y = f2bf(v.y); o.z = f2bf(v.z); o.w = f2bf(v.w);
  reinterpret_cast<ushort4*>(dst)[off] = o;
}

// ---------------- fused QKV GEMM: [8192,3072] = A[M,K] @ W3[3N,K]^T ----------------
__global__ __launch_bounds__(256, 3) void k_gemm3(
    const unsigned short* __restrict__ A,
    const unsigned short* __restrict__ W3,
    const float* __restrict__ bq, const float* __restrict__ bk,
    const float* __restrict__ bv,
    unsigned short* __restrict__ Qo,   // [64][2048][64]
    unsigned short* __restrict__ Ko,   // [64][2048][64]
    unsigned short* __restrict__ Vto,  // [64][64][2048] kv-permuted per 16
    float cexp) {
  const int K = HID;
  __shared__ __align__(16) unsigned short sA[128 * 64];
  __shared__ __align__(16) unsigned short sB[128 * 64];
  const int orig = blockIdx.x + gridDim.x * blockIdx.y;
  const int xcd = orig & 7, idx = orig >> 3;
  const int gm = xcd & 3, gn = xcd >> 2;
  const int m0 = (gm * 16 + (idx & 15)) * 128;
  const int n0 = (gn * 12 + (idx >> 4)) * 128;
  const int tid = threadIdx.x;
  const int lane = tid & 63, wid = tid >> 6;
  const int wr = wid >> 1, wc = wid & 1;
  const int l31 = lane & 31, hi = lane >> 5;

  f32x16 acc[2][2] = {};

  const unsigned short* gA = A + (size_t)m0 * K;
  const unsigned short* gW = W3 + (size_t)n0 * K;

  for (int kt = 0; kt < K; kt += 64) {
#pragma unroll
    for (int i = 0; i < 4; ++i) {
      int c = tid + i * 256;
      int row = c >> 3, col = (c & 7) << 3;
      GLDS(gA + (size_t)row * K + kt + col, (char*)sA + (size_t)c * 16);
      GLDS(gW + (size_t)row * K + kt + col, (char*)sB + (size_t)c * 16);
    }
    __syncthreads();
#pragma unroll
    for (int ks = 0; ks < 4; ++ks) {
      const int cb = ks * 32 + hi * 16; // byte offset within 128B row
      bf16x8 a[2], b[2];
#pragma unroll
      for (int mb = 0; mb < 2; ++mb)
        a[mb] = *reinterpret_cast<const bf16x8*>(
            (const char*)sA + (wr * 64 + mb * 32 + l31) * 128 + cb);
#pragma unroll
      for (int nb = 0; nb < 2; ++nb)
        b[nb] = *reinterpret_cast<const bf16x8*>(
            (const char*)sB + (wc * 64 + nb * 32 + l31) * 128 + cb);
      __builtin_amdgcn_s_setprio(1);
      acc[0][0] = mfma32(a[0], b[0], acc[0][0]);
      acc[0][1] = mfma32(a[0], b[1], acc[0][1]);
      acc[1][0] = mfma32(a[1], b[0], acc[1][0]);
      acc[1][1] = mfma32(a[1], b[1], acc[1][1]);
      __builtin_amdgcn_s_setprio(0);
    }
    __syncthreads();
  }

  const int sect = n0 >> 10; // 0=Q 1=K 2=V
  const float* bias = (sect == 0) ? bq : (sect == 1) ? bk : bv;
  const float sc = (sect == 0) ? cexp : 1.0f;
  const int b = m0 >> 11; // 128-row tile never crosses a batch boundary

  if (sect < 2) {
    unsigned short* C = (sect == 0) ? Qo : Ko;
#pragma unroll
    for (int mb = 0; mb < 2; ++mb) {
      int rbase = m0 + wr * 64 + mb * 32;
#pragma unroll
      for (int nb = 0; nb < 2; ++nb) {
        int colq = (n0 + wc * 64 + nb * 32 + l31) & 1023;
        float bvv = bias[colq];
        int h = colq >> 6, d = colq & 63;
        size_t base = ((size_t)(b * NH + h) * SEQ) * HD + d;
#pragma unroll
        for (int reg = 0; reg < 16; ++reg) {
          int tok = (rbase + (reg & 3) + 8 * (reg >> 2) + 4 * hi) & 2047;
          C[base + (size_t)tok * HD] = f2bf((acc[mb][nb][reg] + bvv) * sc);
        }
      }
    }
  } else {
#pragma unroll
    for (int mb = 0; mb < 2; ++mb) {
      int rbase = m0 + wr * 64 + mb * 32;
#pragma unroll
      for (int nb = 0; nb < 2; ++nb) {
        int colq = (n0 + wc * 64 + nb * 32 + l31) & 1023;
        float bvv = bias[colq];
        int h = colq >> 6, d = colq & 63;
        unsigned short* dst = &Vto[((size_t)(b * NH + h) * HD + d) * SEQ];
#pragma unroll
        for (int g = 0; g < 4; ++g) {
          int T = (rbase + 8 * g + 4 * hi) & 2047; // regs 4g..4g+3 = toks T..T+3
          // kv-permute within each 16-window: 4-group {0,1,2,3}->{0,2,1,3}
          int g4 = (T >> 2) & 3;
          int g2 = (g4 == 1) ? 2 : (g4 == 2) ? 1 : g4;
          int T_s = (T & ~15) | (g2 << 2);
          ushort4 pk;
          pk.x = f2bf(acc[mb][nb][4 * g + 0] + bvv);
          pk.y = f2bf(acc[mb][nb][4 * g + 1] + bvv);
          pk.z = f2bf(acc[mb][nb][4 * g + 2] + bvv);
          pk.w = f2bf(acc[mb][nb][4 * g + 3] + bvv);
          *reinterpret_cast<ushort4*>(&dst[T_s]) = pk;
        }
      }
    }
  }
}

// ---------------- out-proj GEMM: fp32 out = O @ Wo^T + bo ----------------
__global__ __launch_bounds__(256, 3) void k_gemmo(
    const unsigned short* __restrict__ A,
    const unsigned short* __restrict__ W,
    const float* __restrict__ bias,
    float* __restrict__ C) {
  const int K = HID;
  __shared__ __align__(16) unsigned short sA[128 * 64];
  __shared__ __align__(16) unsigned short sB[128 * 64];
  const int orig = blockIdx.x + gridDim.x * blockIdx.y;
  const int xcd = orig & 7, idx = orig >> 3;
  const int gm = xcd & 3, gn = xcd >> 2;
  const int m0 = (gm * 16 + (idx & 15)) * 128;
  const int n0 = (gn * 4 + (idx >> 4)) * 128;
  const int tid = threadIdx.x;
  const int lane = tid & 63, wid = tid >> 6;
  const int wr = wid >> 1, wc = wid & 1;
  const int l31 = lane & 31, hi = lane >> 5;

  f32x16 acc[2][2] = {};

  const unsigned short* gA = A + (size_t)m0 * K;
  const unsigned short* gW = W + (size_t)n0 * K;

  for (int kt = 0; kt < K; kt += 64) {
#pragma unroll
    for (int i = 0; i < 4; ++i) {
      int c = tid + i * 256;
      int row = c >> 3, col = (c & 7) << 3;
      GLDS(gA + (size_t)row * K + kt + col, (char*)sA + (size_t)c * 16);
      GLDS(gW + (size_t)row * K + kt + col, (char*)sB + (size_t)c * 16);
    }
    __syncthreads();
#pragma unroll
    for (int ks = 0; ks < 4; ++ks) {
      const int cb = ks * 32 + hi * 16;
      bf16x8 a[2], b[2];
#pragma unroll
      for (int mb = 0; mb < 2; ++mb)
        a[mb] = *reinterpret_cast<const bf16x8*>(
            (const char*)sA + (wr * 64 + mb * 32 + l31) * 128 + cb);
#pragma unroll
      for (int nb = 0; nb < 2; ++nb)
        b[nb] = *reinterpret_cast<const bf16x8*>(
            (const char*)sB + (wc * 64 + nb * 32 + l31) * 128 + cb);
      __builtin_amdgcn_s_setprio(1);
      acc[0][0] = mfma32(a[0], b[0], acc[0][0]);
      acc[0][1] = mfma32(a[0], b[1], acc[0][1]);
      acc[1][0] = mfma32(a[1], b[0], acc[1][0]);
      acc[1][1] = mfma32(a[1], b[1], acc[1][1]);
      __builtin_amdgcn_s_setprio(0);
    }
    __syncthreads();
  }

#pragma unroll
  for (int mb = 0; mb < 2; ++mb) {
    int rbase = m0 + wr * 64 + mb * 32;
#pragma unroll
    for (int nb = 0; nb < 2; ++nb) {
      int col = n0 + wc * 64 + nb * 32 + l31;
      float bvv = bias[col];
#pragma unroll
      for (int reg = 0; reg < 16; ++reg) {
        int row = rbase + (reg & 3) + 8 * (reg >> 2) + 4 * hi;
        C[(size_t)row * HID + col] = acc[mb][nb][reg] + bvv;
      }
    }
  }
}

// ---------------- attention: 32x32 MFMA, in-register softmax (r18) ----------------
// grid (bh=64, qt=16); 4 waves; wave owns 32 q-rows (band wid*32..+31).
// Per 64-kv tile: GLDS K,V -> barrier -> S -> exp/pack -> PV -> barrier.
// S^T: lane(q=l31,hi): kv = nblk*32 + (reg&3)+8*(reg>>2)+4*hi.
// exp+pack: single asm block (16 v_exp, s_nop, 8 cvt_pk). V kv-permuted ->
// PV B-frag one b128 read. den via mfma(P, ones).
#define KVB 64

__global__ __launch_bounds__(256, 4) void k_attn(
    const unsigned short* __restrict__ Qg,  // [64][2048][64]
    const unsigned short* __restrict__ Kg,  // [64][2048][64]
    const unsigned short* __restrict__ Vt,  // [64][64][2048] kv-permuted
    unsigned short* __restrict__ Og) {      // [8192][1024] bf16
  __shared__ __align__(16) unsigned short smem[128 * 64]; // 16KB

  const int bh = blockIdx.x;
  const int qt = blockIdx.y;
  const int tid = threadIdx.x;
  const int lane = tid & 63, wid = tid >> 6;
  const int l31 = lane & 31, hi = lane >> 5;

  const unsigned short* Kh = Kg + (size_t)bh * SEQ * HD;
  const unsigned short* Vh = Vt + (size_t)bh * HD * SEQ;

  char* sK = (char*)smem;           // [64 kv][128B]
  char* sV = (char*)smem + 8192;    // [64 d ][128B] (kv-permuted cols)

  // staging geometry: chunks c0=tid (row r0 in 0..31), c1=tid+256 (row r0+32)
  const int r0 = tid >> 3, r1 = r0 + 32;
  const int cb0 = SWZ(r0, (tid & 7) << 4) >> 1; // pre-swizzled source short-offset
  const int cb1 = SWZ(r1, (tid & 7) << 4) >> 1;

  // Q B-frags straight from global: row q = wid*32+l31, d = ks*16 + hi*8 + j
  bf16x8 qb[4];
  {
    const unsigned short* Qrow =
        Qg + ((size_t)bh * SEQ + (size_t)qt * 128 + wid * 32 + l31) * HD;
#pragma unroll
    for (int ks = 0; ks < 4; ++ks)
      qb[ks] = *reinterpret_cast<const bf16x8*>(Qrow + ks * 16 + hi * 8);
  }

  const unsigned short onev = (unsigned short)0x3F80; // bf16 1.0
  const bf16x8 ones = {(short)onev, (short)onev, (short)onev, (short)onev,
                       (short)onev, (short)onev, (short)onev, (short)onev};

  f32x16 acco[2] = {};  // O: col d = dblk*32+l31, row q = crow(reg,hi)
  f32x16 accd = {};     // den, same layout

  for (int kt = 0; kt < SEQ; kt += KVB) {
    // stage K [64 kv][64 d] and V^T [64 d][64 kv] (pre-swizzled source)
    GLDS(Kh + (size_t)(kt + r0) * HD + cb0, sK + (size_t)tid * 16);
    GLDS(Kh + (size_t)(kt + r1) * HD + cb1, sK + (size_t)(tid + 256) * 16);
    GLDS(Vh + (size_t)r0 * SEQ + kt + cb0, sV + (size_t)tid * 16);
    GLDS(Vh + (size_t)r1 * SEQ + kt + cb1, sV + (size_t)(tid + 256) * 16);
    __syncthreads(); // staged tiles visible (vmcnt drained)

    // S^T: accs[nblk], kv = nblk*32 + crow(reg,hi), q = l31
    f32x16 accs[2] = {};
#pragma unroll
    for (int ks = 0; ks < 4; ++ks) {
      bf16x8 ka0 = *reinterpret_cast<const bf16x8*>(
          sK + (0 + l31) * 128 + SWZ(l31, ks * 32 + hi * 16));
      bf16x8 ka1 = *reinterpret_cast<const bf16x8*>(
          sK + (32 + l31) * 128 + SWZ(32 + l31, ks * 32 + hi * 16));
      __builtin_amdgcn_s_setprio(1);
      accs[0] = mfma32(ka0, qb[ks], accs[0]);
      accs[1] = mfma32(ka1, qb[ks], accs[1]);
      __builtin_amdgcn_s_setprio(0);
    }

    // P = 2^(S*log2e/32): ONE asm block per 16 values — 16 v_exp then 8
    // cvt_pk, >=8-instr TRANS->VALU spacing by construction.
    bf16x8 pa[4];
#pragma unroll
    for (int nblk = 0; nblk < 2; ++nblk) {
      float p0 = accs[nblk][0],  p1 = accs[nblk][1],  p2 = accs[nblk][2],  p3 = accs[nblk][3];
      float p4 = accs[nblk][4],  p5 = accs[nblk][5],  p6 = accs[nblk][6],  p7 = accs[nblk][7];
      float p8 = accs[nblk][8],  p9 = accs[nblk][9],  p10 = accs[nblk][10], p11 = accs[nblk][11];
      float p12 = accs[nblk][12], p13 = accs[nblk][13], p14 = accs[nblk][14], p15 = accs[nblk][15];
      unsigned w0, w1, w2, w3, w4, w5, w6, w7;
      asm("v_exp_f32 %8, %8\n\t"
          "v_exp_f32 %9, %9\n\t"
          "v_exp_f32 %10, %10\n\t"
          "v_exp_f32 %11, %11\n\t"
          "v_exp_f32 %12, %12\n\t"
          "v_exp_f32 %13, %13\n\t"
          "v_exp_f32 %14, %14\n\t"
          "v_exp_f32 %15, %15\n\t"
          "v_exp_f32 %16, %16\n\t"
          "v_exp_f32 %17, %17\n\t"
          "v_exp_f32 %18, %18\n\t"
          "v_exp_f32 %19, %19\n\t"
          "v_exp_f32 %20, %20\n\t"
          "v_exp_f32 %21, %21\n\t"
          "v_exp_f32 %22, %22\n\t"
          "v_exp_f32 %23, %23\n\t"
          "s_nop 3\n\t"
          "v_cvt_pk_bf16_f32 %0, %8, %9\n\t"
          "v_cvt_pk_bf16_f32 %1, %10, %11\n\t"
          "v_cvt_pk_bf16_f32 %2, %12, %13\n\t"
          "v_cvt_pk_bf16_f32 %3, %14, %15\n\t"
          "v_cvt_pk_bf16_f32 %4, %16, %17\n\t"
          "v_cvt_pk_bf16_f32 %5, %18, %19\n\t"
          "v_cvt_pk_bf16_f32 %6, %20, %21\n\t"
          "v_cvt_pk_bf16_f32 %7, %22, %23"
          : "=&v"(w0), "=&v"(w1), "=&v"(w2), "=&v"(w3),
            "=&v"(w4), "=&v"(w5), "=&v"(w6), "=&v"(w7),
            "+v"(p0), "+v"(p1), "+v"(p2), "+v"(p3),
            "+v"(p4), "+v"(p5), "+v"(p6), "+v"(p7),
            "+v"(p8), "+v"(p9), "+v"(p10), "+v"(p11),
            "+v"(p12), "+v"(p13), "+v"(p14), "+v"(p15));
      uint4 lo4; lo4.x = w0; lo4.y = w1; lo4.z = w2; lo4.w = w3;
      uint4 hi4; hi4.x = w4; hi4.y = w5; hi4.z = w6; hi4.w = w7;
      pa[nblk * 2 + 0] = *reinterpret_cast<bf16x8*>(&lo4);
      pa[nblk * 2 + 1] = *reinterpret_cast<bf16x8*>(&hi4);
    }

    // PV: O += P V ; den += P * ones. Instance i covers kv window i*16..+15;
    // V global layout is kv-permuted so the B-frag is one b128 read.
#pragma unroll
    for (int i = 0; i < 4; ++i) {
      bf16x8 vb[2];
#pragma unroll
      for (int dblk = 0; dblk < 2; ++dblk) {
        const int rsw = dblk * 32 + l31;
        vb[dblk] = *reinterpret_cast<const bf16x8*>(
            sV + rsw * 128 + SWZ(rsw, i * 32 + hi * 16));
      }
      __builtin_amdgcn_s_setprio(1);
      acco[0] = mfma32(pa[i], vb[0], acco[0]);
      acco[1] = mfma32(pa[i], vb[1], acco[1]);
      accd = mfma32(pa[i], ones, accd);
      __builtin_amdgcn_s_setprio(0);
    }

    __syncthreads(); // protect sK/sV before next tile's staging
  }

  // epilogue: O[q][d] = acco/accd; q = crow(reg,hi), d = dblk*32 + l31
  const int b = bh >> 4, h = bh & 15;
#pragma unroll
  for (int reg = 0; reg < 16; ++reg) {
    int q = (reg & 3) + 8 * (reg >> 2) + 4 * hi;
    int tok = qt * 128 + wid * 32 + q;
    float rd = 1.0f / accd[reg];
    size_t rowoff = (size_t)(b * SEQ + tok) * HID + h * 64;
    Og[rowoff + l31] = f2bf(acco[0][reg] * rd);
    Og[rowoff + 32 + l31] = f2bf(acco[1][reg] * rd);
  }
}

// ---------------- launch ----------------
extern "C" void kernel_launch(void* const* d_in, const int* in_sizes, int n_in,
                              void* d_out, int out_size, void* d_ws, size_t ws_size,
                              hipStream_t stream) {
  (void)in_sizes; (void)n_in; (void)out_size; (void)ws_size;
  const float* x = (const float*)d_in[0];
  const float* Wq = (const float*)d_in[1];
  const float* bq = (const float*)d_in[2];
  const float* Wk = (const float*)d_in[3];
  const float* bk = (const float*)d_in[4];
  const float* Wv = (const float*)d_in[5];
  const float* bv = (const float*)d_in[6];
  const float* Wo = (const float*)d_in[7];
  const float* bo = (const float*)d_in[8];

  unsigned short* ws = (unsigned short*)d_ws;
  unsigned short* xb = ws;
  unsigned short* wqb = xb + (size_t)MTOT * HID;  // Wq;Wk;Wv;Wo contiguous
  unsigned short* wob = wqb + 3 * (size_t)HID * HID;
  unsigned short* qb = wob + (size_t)HID * HID;   // [64][2048][64]
  unsigned short* kb = qb + (size_t)MTOT * HID;   // [64][2048][64]
  unsigned short* vtb = kb + (size_t)MTOT * HID;  // [64][64][2048] kv-permuted
  unsigned short* ob = vtb + (size_t)MTOT * HID;  // [8192][1024]

  const float cexp = 0.04508422f; // log2(e)/32 — attn computes 2^(S*cexp)

  k_cvt_all<<<(MTOT * HID / 4 + 4 * (HID * HID / 4)) / 256, 256, 0, stream>>>(
      x, Wq, Wk, Wv, Wo, ws);

  k_gemm3<<<dim3(64, 24), 256, 0, stream>>>(
      xb, wqb, bq, bk, bv, qb, kb, vtb, cexp);

  k_attn<<<dim3(64, SEQ / 128), 256, 0, stream>>>(qb, kb, vtb, ob);

  k_gemmo<<<dim3(64, 8), 256, 0, stream>>>(ob, wob, bo, (float*)d_out);
}

// Round 22
// 190.559 us; speedup vs baseline: 1.2211x; 1.2211x over previous
//
#include <hip/hip_runtime.h>
#include <stdint.h>

// MultiHeadAttention: x[4,2048,1024] fp32; Wq/Wk/Wv/Wo [1024,1024]; biases zero.
// out = softmax((xWq^T)(xWk^T)^T / 32) (xWv^T) Wo^T + bo   (16 heads, d=64)
//
// Pipeline (bf16 MFMA, fp32 accum):
//  k_cvt_all: x,W* fp32->bf16 (single fused launch)
//  k_gemm3/k_gemmo: 128x128 tile, 4 waves (2x2, 64x64/wave), BK=64,
//     32x32x16 MFMA inner loop. r22: LDS XOR-swizzled BOTH sides (attn's
//     proven pattern — pre-swizzled global_load_lds source + SWZ'd reads);
//     r21's linear LDS with 32-lane l31 reads was a 32-way bank conflict
//     (4.4e7 cyc, MfmaUtil 18) — T2 textbook case.
//     XCD-partitioned grid. V stored [bh][d][kv], kv PRE-PERMUTED per
//     16-token window ({0,1,2,3}->{0,2,1,3}); Q pre-scaled log2e/32.
//  k_attn: 32x32x16 MFMA flash attention, fully in-register softmax (r18
//     structure): GLDS K,V -> barrier -> S -> exp/pack -> PV -> barrier;
//     exp+pack = ONE asm block (16 v_exp, s_nop, 8 cvt_pk — TRANS->VALU
//     spacing by construction); den via mfma(P, ones).

#define HID 1024
#define NH 16
#define HD 64
#define BB 4
#define SEQ 2048
#define MTOT (BB * SEQ) // 8192

typedef short bf16x8 __attribute__((ext_vector_type(8)));
typedef float f32x16 __attribute__((ext_vector_type(16)));

// swizzle: byte col within a 128B row, XORed by row&7 (16B granular)
#define SWZ(row, cb) ((cb) ^ (((row) & 7) << 4))

#define GLDS(gp, lp) __builtin_amdgcn_global_load_lds( \
    (const __attribute__((address_space(1))) void*)(gp), \
    (__attribute__((address_space(3))) void*)(lp), 16, 0, 0)

// f32 -> bf16 RNE, manual bit-twiddle (proven; (__bf16) cast failed in r12)
static __device__ __forceinline__ unsigned short f2bf(float f) {
  unsigned u = __float_as_uint(f);
  u += 0x7fffu + ((u >> 16) & 1u); // RNE
  return (unsigned short)(u >> 16);
}

static __device__ __forceinline__ f32x16 mfma32(bf16x8 a, bf16x8 b, f32x16 c) {
  return __builtin_amdgcn_mfma_f32_32x32x16_bf16(a, b, c, 0, 0, 0);
}

// ---------------- fp32 -> bf16 convert, all tensors, one launch ----------------
__global__ void k_cvt_all(const float* __restrict__ x,
                          const float* __restrict__ Wq, const float* __restrict__ Wk,
                          const float* __restrict__ Wv, const float* __restrict__ Wo,
                          unsigned short* __restrict__ ws) {
  const int X4 = MTOT * HID / 4;
  const int W4 = HID * HID / 4;
  int i = blockIdx.x * blockDim.x + threadIdx.x;
  const float* src;
  unsigned short* dst;
  int off;
  if (i < X4) {
    src = x; dst = ws; off = i;
  } else {
    int j = i - X4;
    int w = j / W4;
    off = j - w * W4;
    src = (w == 0) ? Wq : (w == 1) ? Wk : (w == 2) ? Wv : Wo;
    dst = ws + (size_t)MTOT * HID + (size_t)w * HID * HID;
  }
  float4 v = reinterpret_cast<const float4*>(src)[off];
  ushort4 o;
  o.x = f2bf(v.x); o.y = f2bf(v.y); o.z = f2bf(v.z); o.w = f2bf(v.w);
  reinterpret_cast<ushort4*>(dst)[off] = o;
}

// ---------------- fused QKV GEMM: [8192,3072] = A[M,K] @ W3[3N,K]^T ----------------
__global__ __launch_bounds__(256, 3) void k_gemm3(
    const unsigned short* __restrict__ A,
    const unsigned short* __restrict__ W3,
    const float* __restrict__ bq, const float* __restrict__ bk,
    const float* __restrict__ bv,
    unsigned short* __restrict__ Qo,   // [64][2048][64]
    unsigned short* __restrict__ Ko,   // [64][2048][64]
    unsigned short* __restrict__ Vto,  // [64][64][2048] kv-permuted per 16
    float cexp) {
  const int K = HID;
  __shared__ __align__(16) unsigned short sA[128 * 64];
  __shared__ __align__(16) unsigned short sB[128 * 64];
  const int orig = blockIdx.x + gridDim.x * blockIdx.y;
  const int xcd = orig & 7, idx = orig >> 3;
  const int gm = xcd & 3, gn = xcd >> 2;
  const int m0 = (gm * 16 + (idx & 15)) * 128;
  const int n0 = (gn * 12 + (idx >> 4)) * 128;
  const int tid = threadIdx.x;
  const int lane = tid & 63, wid = tid >> 6;
  const int wr = wid >> 1, wc = wid & 1;
  const int l31 = lane & 31, hi = lane >> 5;

  f32x16 acc[2][2] = {};

  const unsigned short* gA = A + (size_t)m0 * K;
  const unsigned short* gW = W3 + (size_t)n0 * K;

  for (int kt = 0; kt < K; kt += 64) {
    // stage with pre-swizzled global source, linear LDS dest (rule 21)
#pragma unroll
    for (int i = 0; i < 4; ++i) {
      int c = tid + i * 256;
      int row = c >> 3;
      int cs = SWZ(row, (c & 7) << 4) >> 1; // short offset within 64-short row
      GLDS(gA + (size_t)row * K + kt + cs, (char*)sA + (size_t)c * 16);
      GLDS(gW + (size_t)row * K + kt + cs, (char*)sB + (size_t)c * 16);
    }
    __syncthreads();
#pragma unroll
    for (int ks = 0; ks < 4; ++ks) {
      const int cb = ks * 32 + hi * 16; // byte offset within 128B row
      const int cbs = SWZ(l31, cb);     // row&7 == l31&7 for all frag rows
      bf16x8 a[2], b[2];
#pragma unroll
      for (int mb = 0; mb < 2; ++mb)
        a[mb] = *reinterpret_cast<const bf16x8*>(
            (const char*)sA + (wr * 64 + mb * 32 + l31) * 128 + cbs);
#pragma unroll
      for (int nb = 0; nb < 2; ++nb)
        b[nb] = *reinterpret_cast<const bf16x8*>(
            (const char*)sB + (wc * 64 + nb * 32 + l31) * 128 + cbs);
      __builtin_amdgcn_s_setprio(1);
      acc[0][0] = mfma32(a[0], b[0], acc[0][0]);
      acc[0][1] = mfma32(a[0], b[1], acc[0][1]);
      acc[1][0] = mfma32(a[1], b[0], acc[1][0]);
      acc[1][1] = mfma32(a[1], b[1], acc[1][1]);
      __builtin_amdgcn_s_setprio(0);
    }
    __syncthreads();
  }

  const int sect = n0 >> 10; // 0=Q 1=K 2=V
  const float* bias = (sect == 0) ? bq : (sect == 1) ? bk : bv;
  const float sc = (sect == 0) ? cexp : 1.0f;
  const int b = m0 >> 11; // 128-row tile never crosses a batch boundary

  if (sect < 2) {
    unsigned short* C = (sect == 0) ? Qo : Ko;
#pragma unroll
    for (int mb = 0; mb < 2; ++mb) {
      int rbase = m0 + wr * 64 + mb * 32;
#pragma unroll
      for (int nb = 0; nb < 2; ++nb) {
        int colq = (n0 + wc * 64 + nb * 32 + l31) & 1023;
        float bvv = bias[colq];
        int h = colq >> 6, d = colq & 63;
        size_t base = ((size_t)(b * NH + h) * SEQ) * HD + d;
#pragma unroll
        for (int reg = 0; reg < 16; ++reg) {
          int tok = (rbase + (reg & 3) + 8 * (reg >> 2) + 4 * hi) & 2047;
          C[base + (size_t)tok * HD] = f2bf((acc[mb][nb][reg] + bvv) * sc);
        }
      }
    }
  } else {
#pragma unroll
    for (int mb = 0; mb < 2; ++mb) {
      int rbase = m0 + wr * 64 + mb * 32;
#pragma unroll
      for (int nb = 0; nb < 2; ++nb) {
        int colq = (n0 + wc * 64 + nb * 32 + l31) & 1023;
        float bvv = bias[colq];
        int h = colq >> 6, d = colq & 63;
        unsigned short* dst = &Vto[((size_t)(b * NH + h) * HD + d) * SEQ];
#pragma unroll
        for (int g = 0; g < 4; ++g) {
          int T = (rbase + 8 * g + 4 * hi) & 2047; // regs 4g..4g+3 = toks T..T+3
          // kv-permute within each 16-window: 4-group {0,1,2,3}->{0,2,1,3}
          int g4 = (T >> 2) & 3;
          int g2 = (g4 == 1) ? 2 : (g4 == 2) ? 1 : g4;
          int T_s = (T & ~15) | (g2 << 2);
          ushort4 pk;
          pk.x = f2bf(acc[mb][nb][4 * g + 0] + bvv);
          pk.y = f2bf(acc[mb][nb][4 * g + 1] + bvv);
          pk.z = f2bf(acc[mb][nb][4 * g + 2] + bvv);
          pk.w = f2bf(acc[mb][nb][4 * g + 3] + bvv);
          *reinterpret_cast<ushort4*>(&dst[T_s]) = pk;
        }
      }
    }
  }
}

// ---------------- out-proj GEMM: fp32 out = O @ Wo^T + bo ----------------
__global__ __launch_bounds__(256, 3) void k_gemmo(
    const unsigned short* __restrict__ A,
    const unsigned short* __restrict__ W,
    const float* __restrict__ bias,
    float* __restrict__ C) {
  const int K = HID;
  __shared__ __align__(16) unsigned short sA[128 * 64];
  __shared__ __align__(16) unsigned short sB[128 * 64];
  const int orig = blockIdx.x + gridDim.x * blockIdx.y;
  const int xcd = orig & 7, idx = orig >> 3;
  const int gm = xcd & 3, gn = xcd >> 2;
  const int m0 = (gm * 16 + (idx & 15)) * 128;
  const int n0 = (gn * 4 + (idx >> 4)) * 128;
  const int tid = threadIdx.x;
  const int lane = tid & 63, wid = tid >> 6;
  const int wr = wid >> 1, wc = wid & 1;
  const int l31 = lane & 31, hi = lane >> 5;

  f32x16 acc[2][2] = {};

  const unsigned short* gA = A + (size_t)m0 * K;
  const unsigned short* gW = W + (size_t)n0 * K;

  for (int kt = 0; kt < K; kt += 64) {
#pragma unroll
    for (int i = 0; i < 4; ++i) {
      int c = tid + i * 256;
      int row = c >> 3;
      int cs = SWZ(row, (c & 7) << 4) >> 1;
      GLDS(gA + (size_t)row * K + kt + cs, (char*)sA + (size_t)c * 16);
      GLDS(gW + (size_t)row * K + kt + cs, (char*)sB + (size_t)c * 16);
    }
    __syncthreads();
#pragma unroll
    for (int ks = 0; ks < 4; ++ks) {
      const int cb = ks * 32 + hi * 16;
      const int cbs = SWZ(l31, cb);
      bf16x8 a[2], b[2];
#pragma unroll
      for (int mb = 0; mb < 2; ++mb)
        a[mb] = *reinterpret_cast<const bf16x8*>(
            (const char*)sA + (wr * 64 + mb * 32 + l31) * 128 + cbs);
#pragma unroll
      for (int nb = 0; nb < 2; ++nb)
        b[nb] = *reinterpret_cast<const bf16x8*>(
            (const char*)sB + (wc * 64 + nb * 32 + l31) * 128 + cbs);
      __builtin_amdgcn_s_setprio(1);
      acc[0][0] = mfma32(a[0], b[0], acc[0][0]);
      acc[0][1] = mfma32(a[0], b[1], acc[0][1]);
      acc[1][0] = mfma32(a[1], b[0], acc[1][0]);
      acc[1][1] = mfma32(a[1], b[1], acc[1][1]);
      __builtin_amdgcn_s_setprio(0);
    }
    __syncthreads();
  }

#pragma unroll
  for (int mb = 0; mb < 2; ++mb) {
    int rbase = m0 + wr * 64 + mb * 32;
#pragma unroll
    for (int nb = 0; nb < 2; ++nb) {
      int col = n0 + wc * 64 + nb * 32 + l31;
      float bvv = bias[col];
#pragma unroll
      for (int reg = 0; reg < 16; ++reg) {
        int row = rbase + (reg & 3) + 8 * (reg >> 2) + 4 * hi;
        C[(size_t)row * HID + col] = acc[mb][nb][reg] + bvv;
      }
    }
  }
}

// ---------------- attention: 32x32 MFMA, in-register softmax (r18) ----------------
// grid (bh=64, qt=16); 4 waves; wave owns 32 q-rows (band wid*32..+31).
// Per 64-kv tile: GLDS K,V -> barrier -> S -> exp/pack -> PV -> barrier.
// S^T: lane(q=l31,hi): kv = nblk*32 + (reg&3)+8*(reg>>2)+4*hi.
// exp+pack: single asm block (16 v_exp, s_nop, 8 cvt_pk). V kv-permuted ->
// PV B-frag one b128 read. den via mfma(P, ones).
#define KVB 64

__global__ __launch_bounds__(256, 4) void k_attn(
    const unsigned short* __restrict__ Qg,  // [64][2048][64]
    const unsigned short* __restrict__ Kg,  // [64][2048][64]
    const unsigned short* __restrict__ Vt,  // [64][64][2048] kv-permuted
    unsigned short* __restrict__ Og) {      // [8192][1024] bf16
  __shared__ __align__(16) unsigned short smem[128 * 64]; // 16KB

  const int bh = blockIdx.x;
  const int qt = blockIdx.y;
  const int tid = threadIdx.x;
  const int lane = tid & 63, wid = tid >> 6;
  const int l31 = lane & 31, hi = lane >> 5;

  const unsigned short* Kh = Kg + (size_t)bh * SEQ * HD;
  const unsigned short* Vh = Vt + (size_t)bh * HD * SEQ;

  char* sK = (char*)smem;           // [64 kv][128B]
  char* sV = (char*)smem + 8192;    // [64 d ][128B] (kv-permuted cols)

  // staging geometry: chunks c0=tid (row r0 in 0..31), c1=tid+256 (row r0+32)
  const int r0 = tid >> 3, r1 = r0 + 32;
  const int cb0 = SWZ(r0, (tid & 7) << 4) >> 1; // pre-swizzled source short-offset
  const int cb1 = SWZ(r1, (tid & 7) << 4) >> 1;

  // Q B-frags straight from global: row q = wid*32+l31, d = ks*16 + hi*8 + j
  bf16x8 qb[4];
  {
    const unsigned short* Qrow =
        Qg + ((size_t)bh * SEQ + (size_t)qt * 128 + wid * 32 + l31) * HD;
#pragma unroll
    for (int ks = 0; ks < 4; ++ks)
      qb[ks] = *reinterpret_cast<const bf16x8*>(Qrow + ks * 16 + hi * 8);
  }

  const unsigned short onev = (unsigned short)0x3F80; // bf16 1.0
  const bf16x8 ones = {(short)onev, (short)onev, (short)onev, (short)onev,
                       (short)onev, (short)onev, (short)onev, (short)onev};

  f32x16 acco[2] = {};  // O: col d = dblk*32+l31, row q = crow(reg,hi)
  f32x16 accd = {};     // den, same layout

  for (int kt = 0; kt < SEQ; kt += KVB) {
    // stage K [64 kv][64 d] and V^T [64 d][64 kv] (pre-swizzled source)
    GLDS(Kh + (size_t)(kt + r0) * HD + cb0, sK + (size_t)tid * 16);
    GLDS(Kh + (size_t)(kt + r1) * HD + cb1, sK + (size_t)(tid + 256) * 16);
    GLDS(Vh + (size_t)r0 * SEQ + kt + cb0, sV + (size_t)tid * 16);
    GLDS(Vh + (size_t)r1 * SEQ + kt + cb1, sV + (size_t)(tid + 256) * 16);
    __syncthreads(); // staged tiles visible (vmcnt drained)

    // S^T: accs[nblk], kv = nblk*32 + crow(reg,hi), q = l31
    f32x16 accs[2] = {};
#pragma unroll
    for (int ks = 0; ks < 4; ++ks) {
      bf16x8 ka0 = *reinterpret_cast<const bf16x8*>(
          sK + (0 + l31) * 128 + SWZ(l31, ks * 32 + hi * 16));
      bf16x8 ka1 = *reinterpret_cast<const bf16x8*>(
          sK + (32 + l31) * 128 + SWZ(32 + l31, ks * 32 + hi * 16));
      __builtin_amdgcn_s_setprio(1);
      accs[0] = mfma32(ka0, qb[ks], accs[0]);
      accs[1] = mfma32(ka1, qb[ks], accs[1]);
      __builtin_amdgcn_s_setprio(0);
    }

    // P = 2^(S*log2e/32): ONE asm block per 16 values — 16 v_exp then 8
    // cvt_pk, >=8-instr TRANS->VALU spacing by construction.
    bf16x8 pa[4];
#pragma unroll
    for (int nblk = 0; nblk < 2; ++nblk) {
      float p0 = accs[nblk][0],  p1 = accs[nblk][1],  p2 = accs[nblk][2],  p3 = accs[nblk][3];
      float p4 = accs[nblk][4],  p5 = accs[nblk][5],  p6 = accs[nblk][6],  p7 = accs[nblk][7];
      float p8 = accs[nblk][8],  p9 = accs[nblk][9],  p10 = accs[nblk][10], p11 = accs[nblk][11];
      float p12 = accs[nblk][12], p13 = accs[nblk][13], p14 = accs[nblk][14], p15 = accs[nblk][15];
      unsigned w0, w1, w2, w3, w4, w5, w6, w7;
      asm("v_exp_f32 %8, %8\n\t"
          "v_exp_f32 %9, %9\n\t"
          "v_exp_f32 %10, %10\n\t"
          "v_exp_f32 %11, %11\n\t"
          "v_exp_f32 %12, %12\n\t"
          "v_exp_f32 %13, %13\n\t"
          "v_exp_f32 %14, %14\n\t"
          "v_exp_f32 %15, %15\n\t"
          "v_exp_f32 %16, %16\n\t"
          "v_exp_f32 %17, %17\n\t"
          "v_exp_f32 %18, %18\n\t"
          "v_exp_f32 %19, %19\n\t"
          "v_exp_f32 %20, %20\n\t"
          "v_exp_f32 %21, %21\n\t"
          "v_exp_f32 %22, %22\n\t"
          "v_exp_f32 %23, %23\n\t"
          "s_nop 3\n\t"
          "v_cvt_pk_bf16_f32 %0, %8, %9\n\t"
          "v_cvt_pk_bf16_f32 %1, %10, %11\n\t"
          "v_cvt_pk_bf16_f32 %2, %12, %13\n\t"
          "v_cvt_pk_bf16_f32 %3, %14, %15\n\t"
          "v_cvt_pk_bf16_f32 %4, %16, %17\n\t"
          "v_cvt_pk_bf16_f32 %5, %18, %19\n\t"
          "v_cvt_pk_bf16_f32 %6, %20, %21\n\t"
          "v_cvt_pk_bf16_f32 %7, %22, %23"
          : "=&v"(w0), "=&v"(w1), "=&v"(w2), "=&v"(w3),
            "=&v"(w4), "=&v"(w5), "=&v"(w6), "=&v"(w7),
            "+v"(p0), "+v"(p1), "+v"(p2), "+v"(p3),
            "+v"(p4), "+v"(p5), "+v"(p6), "+v"(p7),
            "+v"(p8), "+v"(p9), "+v"(p10), "+v"(p11),
            "+v"(p12), "+v"(p13), "+v"(p14), "+v"(p15));
      uint4 lo4; lo4.x = w0; lo4.y = w1; lo4.z = w2; lo4.w = w3;
      uint4 hi4; hi4.x = w4; hi4.y = w5; hi4.z = w6; hi4.w = w7;
      pa[nblk * 2 + 0] = *reinterpret_cast<bf16x8*>(&lo4);
      pa[nblk * 2 + 1] = *reinterpret_cast<bf16x8*>(&hi4);
    }

    // PV: O += P V ; den += P * ones. Instance i covers kv window i*16..+15;
    // V global layout is kv-permuted so the B-frag is one b128 read.
#pragma unroll
    for (int i = 0; i < 4; ++i) {
      bf16x8 vb[2];
#pragma unroll
      for (int dblk = 0; dblk < 2; ++dblk) {
        const int rsw = dblk * 32 + l31;
        vb[dblk] = *reinterpret_cast<const bf16x8*>(
            sV + rsw * 128 + SWZ(rsw, i * 32 + hi * 16));
      }
      __builtin_amdgcn_s_setprio(1);
      acco[0] = mfma32(pa[i], vb[0], acco[0]);
      acco[1] = mfma32(pa[i], vb[1], acco[1]);
      accd = mfma32(pa[i], ones, accd);
      __builtin_amdgcn_s_setprio(0);
    }

    __syncthreads(); // protect sK/sV before next tile's staging
  }

  // epilogue: O[q][d] = acco/accd; q = crow(reg,hi), d = dblk*32 + l31
  const int b = bh >> 4, h = bh & 15;
#pragma unroll
  for (int reg = 0; reg < 16; ++reg) {
    int q = (reg & 3) + 8 * (reg >> 2) + 4 * hi;
    int tok = qt * 128 + wid * 32 + q;
    float rd = 1.0f / accd[reg];
    size_t rowoff = (size_t)(b * SEQ + tok) * HID + h * 64;
    Og[rowoff + l31] = f2bf(acco[0][reg] * rd);
    Og[rowoff + 32 + l31] = f2bf(acco[1][reg] * rd);
  }
}

// ---------------- launch ----------------
extern "C" void kernel_launch(void* const* d_in, const int* in_sizes, int n_in,
                              void* d_out, int out_size, void* d_ws, size_t ws_size,
                              hipStream_t stream) {
  (void)in_sizes; (void)n_in; (void)out_size; (void)ws_size;
  const float* x = (const float*)d_in[0];
  const float* Wq = (const float*)d_in[1];
  const float* bq = (const float*)d_in[2];
  const float* Wk = (const float*)d_in[3];
  const float* bk = (const float*)d_in[4];
  const float* Wv = (const float*)d_in[5];
  const float* bv = (const float*)d_in[6];
  const float* Wo = (const float*)d_in[7];
  const float* bo = (const float*)d_in[8];

  unsigned short* ws = (unsigned short*)d_ws;
  unsigned short* xb = ws;
  unsigned short* wqb = xb + (size_t)MTOT * HID;  // Wq;Wk;Wv;Wo contiguous
  unsigned short* wob = wqb + 3 * (size_t)HID * HID;
  unsigned short* qb = wob + (size_t)HID * HID;   // [64][2048][64]
  unsigned short* kb = qb + (size_t)MTOT * HID;   // [64][2048][64]
  unsigned short* vtb = kb + (size_t)MTOT * HID;  // [64][64][2048] kv-permuted
  unsigned short* ob = vtb + (size_t)MTOT * HID;  // [8192][1024]

  const float cexp = 0.04508422f; // log2(e)/32 — attn computes 2^(S*cexp)

  k_cvt_all<<<(MTOT * HID / 4 + 4 * (HID * HID / 4)) / 256, 256, 0, stream>>>(
      x, Wq, Wk, Wv, Wo, ws);

  k_gemm3<<<dim3(64, 24), 256, 0, stream>>>(
      xb, wqb, bq, bk, bv, qb, kb, vtb, cexp);

  k_attn<<<dim3(64, SEQ / 128), 256, 0, stream>>>(qb, kb, vtb, ob);

  k_gemmo<<<dim3(64, 8), 256, 0, stream>>>(ob, wob, bo, (float*)d_out);
}

// Round 23
// 188.943 us; speedup vs baseline: 1.2315x; 1.0086x over previous
//
#include <hip/hip_runtime.h>
#include <stdint.h>

// MultiHeadAttention: x[4,2048,1024] fp32; Wq/Wk/Wv/Wo [1024,1024]; biases zero.
// out = softmax((xWq^T)(xWk^T)^T / 32) (xWv^T) Wo^T + bo   (16 heads, d=64)
//
// FINAL CONFIG (r18 = best measured, 188.2us):
//  k_cvt_all: x,W* fp32->bf16 (single fused launch)
//  k_gemm3: fused QKV projection, N=3072, 128x128 tile, 16x16x32 MFMA,
//     global_load_lds staging, XCD-partitioned grid. V stored [bh][d][kv]
//     kv PRE-PERMUTED per 16-token window ({0,1,2,3}->{0,2,1,3}) so attn's
//     PV B-frag is one b128 LDS read. Q pre-scaled by log2(e)/32.
//     (r21/r22: 32x32 MFMA inner loop = no gain, 2-barrier GEMM is
//     drain-bound; r20: (256,3) occupancy = null. 16x16 @(256,2) kept.)
//  k_attn: 32x32x16 MFMA flash attention, fully in-register softmax.
//     GLDS K,V -> barrier -> S -> exp/pack -> PV -> barrier (deterministic;
//     ping-pong/dbuf variants raced or regressed). exp+pack = ONE asm block
//     (16 v_exp, s_nop, 8 cvt_pk — TRANS->VALU hazard spacing by
//     construction; lone asm v_exp, __expf, and (__bf16) casts all corrupt).
//     den via mfma(P, ones) — lands in acco's exact fragment layout.
//  k_gemmo: O @ Wo^T + bo -> fp32 d_out, XCD-partitioned grid.

#define HID 1024
#define NH 16
#define HD 64
#define BB 4
#define SEQ 2048
#define MTOT (BB * SEQ) // 8192

typedef short bf16x8 __attribute__((ext_vector_type(8)));
typedef float f32x4 __attribute__((ext_vector_type(4)));
typedef float f32x16 __attribute__((ext_vector_type(16)));

// swizzle: byte col within a 128B row, XORed by row&7 (16B granular)
#define SWZ(row, cb) ((cb) ^ (((row) & 7) << 4))

#define GLDS(gp, lp) __builtin_amdgcn_global_load_lds( \
    (const __attribute__((address_space(1))) void*)(gp), \
    (__attribute__((address_space(3))) void*)(lp), 16, 0, 0)

// f32 -> bf16 RNE, manual bit-twiddle (proven; (__bf16) cast failed in r12)
static __device__ __forceinline__ unsigned short f2bf(float f) {
  unsigned u = __float_as_uint(f);
  u += 0x7fffu + ((u >> 16) & 1u); // RNE
  return (unsigned short)(u >> 16);
}

static __device__ __forceinline__ f32x4 mfma16(bf16x8 a, bf16x8 b, f32x4 c) {
  return __builtin_amdgcn_mfma_f32_16x16x32_bf16(a, b, c, 0, 0, 0);
}
static __device__ __forceinline__ f32x16 mfma32(bf16x8 a, bf16x8 b, f32x16 c) {
  return __builtin_amdgcn_mfma_f32_32x32x16_bf16(a, b, c, 0, 0, 0);
}

// ---------------- fp32 -> bf16 convert, all tensors, one launch ----------------
__global__ void k_cvt_all(const float* __restrict__ x,
                          const float* __restrict__ Wq, const float* __restrict__ Wk,
                          const float* __restrict__ Wv, const float* __restrict__ Wo,
                          unsigned short* __restrict__ ws) {
  const int X4 = MTOT * HID / 4;
  const int W4 = HID * HID / 4;
  int i = blockIdx.x * blockDim.x + threadIdx.x;
  const float* src;
  unsigned short* dst;
  int off;
  if (i < X4) {
    src = x; dst = ws; off = i;
  } else {
    int j = i - X4;
    int w = j / W4;
    off = j - w * W4;
    src = (w == 0) ? Wq : (w == 1) ? Wk : (w == 2) ? Wv : Wo;
    dst = ws + (size_t)MTOT * HID + (size_t)w * HID * HID;
  }
  float4 v = reinterpret_cast<const float4*>(src)[off];
  ushort4 o;
  o.x = f2bf(v.x); o.y = f2bf(v.y); o.z = f2bf(v.z); o.w = f2bf(v.w);
  reinterpret_cast<ushort4*>(dst)[off] = o;
}

// ---------------- fused QKV GEMM: [8192,3072] = A[M,K] @ W3[3N,K]^T ----------------
__global__ __launch_bounds__(256, 2) void k_gemm3(
    const unsigned short* __restrict__ A,
    const unsigned short* __restrict__ W3,
    const float* __restrict__ bq, const float* __restrict__ bk,
    const float* __restrict__ bv,
    unsigned short* __restrict__ Qo,   // [64][2048][64]
    unsigned short* __restrict__ Ko,   // [64][2048][64]
    unsigned short* __restrict__ Vto,  // [64][64][2048] kv-permuted per 16
    float cexp) {
  const int K = HID;
  __shared__ __align__(16) unsigned short sA[128 * 64];
  __shared__ __align__(16) unsigned short sB[128 * 64];
  const int orig = blockIdx.x + gridDim.x * blockIdx.y;
  const int xcd = orig & 7, idx = orig >> 3;
  const int gm = xcd & 3, gn = xcd >> 2;
  const int m0 = (gm * 16 + (idx & 15)) * 128;
  const int n0 = (gn * 12 + (idx >> 4)) * 128;
  const int tid = threadIdx.x;
  const int lane = tid & 63, wid = tid >> 6;
  const int wr = wid >> 1, wc = wid & 1;
  const int lr = lane & 15, lg = lane >> 4;

  f32x4 acc[4][4] = {};

  const unsigned short* gA = A + (size_t)m0 * K;
  const unsigned short* gW = W3 + (size_t)n0 * K;

  for (int kt = 0; kt < K; kt += 64) {
#pragma unroll
    for (int i = 0; i < 4; ++i) {
      int c = tid + i * 256;
      int row = c >> 3, col = (c & 7) << 3;
      GLDS(gA + (size_t)row * K + kt + col, (char*)sA + (size_t)c * 16);
      GLDS(gW + (size_t)row * K + kt + col, (char*)sB + (size_t)c * 16);
    }
    __syncthreads();
#pragma unroll
    for (int kk = 0; kk < 64; kk += 32) {
      bf16x8 a[4], b[4];
      const int co = kk + lg * 8;
#pragma unroll
      for (int m = 0; m < 4; ++m)
        a[m] = *reinterpret_cast<const bf16x8*>(sA + (wr * 64 + m * 16 + lr) * 64 + co);
#pragma unroll
      for (int n = 0; n < 4; ++n)
        b[n] = *reinterpret_cast<const bf16x8*>(sB + (wc * 64 + n * 16 + lr) * 64 + co);
      __builtin_amdgcn_s_setprio(1);
#pragma unroll
      for (int m = 0; m < 4; ++m)
#pragma unroll
        for (int n = 0; n < 4; ++n)
          acc[m][n] = mfma16(a[m], b[n], acc[m][n]);
      __builtin_amdgcn_s_setprio(0);
    }
    __syncthreads();
  }

  const int sect = n0 >> 10; // 0=Q 1=K 2=V
  const float* bias = (sect == 0) ? bq : (sect == 1) ? bk : bv;
  const float sc = (sect == 0) ? cexp : 1.0f;

  if (sect < 2) {
    unsigned short* C = (sect == 0) ? Qo : Ko;
#pragma unroll
    for (int m = 0; m < 4; ++m) {
      int row0 = m0 + wr * 64 + m * 16 + lg * 4;
      int b = row0 >> 11;
#pragma unroll
      for (int n = 0; n < 4; ++n) {
        int colq = (n0 + wc * 64 + n * 16 + lr) & 1023;
        float bvv = bias[colq];
        int h = colq >> 6, d = colq & 63;
        size_t base = ((size_t)(b * NH + h) * SEQ) * HD + d;
#pragma unroll
        for (int r = 0; r < 4; ++r) {
          int tok = (row0 + r) & 2047;
          C[base + (size_t)tok * HD] = f2bf((acc[m][n][r] + bvv) * sc);
        }
      }
    }
  } else {
#pragma unroll
    for (int m = 0; m < 4; ++m) {
      int row0 = m0 + wr * 64 + m * 16 + lg * 4;
      int b = row0 >> 11;
      int tok0 = row0 & 2047;
      // kv-permute within each 16-window: 4-group g {0,1,2,3} -> {0,2,1,3}
      int g = (tok0 >> 2) & 3;
      int g2 = (g == 1) ? 2 : (g == 2) ? 1 : g;
      int tok_s = (tok0 & ~15) | (g2 << 2);
#pragma unroll
      for (int n = 0; n < 4; ++n) {
        int colq = (n0 + wc * 64 + n * 16 + lr) & 1023;
        float bvv = bias[colq];
        int h = colq >> 6, d = colq & 63;
        ushort4 pk;
        pk.x = f2bf(acc[m][n][0] + bvv);
        pk.y = f2bf(acc[m][n][1] + bvv);
        pk.z = f2bf(acc[m][n][2] + bvv);
        pk.w = f2bf(acc[m][n][3] + bvv);
        *reinterpret_cast<ushort4*>(&Vto[((size_t)(b * NH + h) * HD + d) * SEQ + tok_s]) = pk;
      }
    }
  }
}

// ---------------- out-proj GEMM: fp32 out = O @ Wo^T + bo ----------------
__global__ __launch_bounds__(256, 2) void k_gemmo(
    const unsigned short* __restrict__ A,
    const unsigned short* __restrict__ W,
    const float* __restrict__ bias,
    float* __restrict__ C) {
  const int K = HID;
  __shared__ __align__(16) unsigned short sA[128 * 64];
  __shared__ __align__(16) unsigned short sB[128 * 64];
  const int orig = blockIdx.x + gridDim.x * blockIdx.y;
  const int xcd = orig & 7, idx = orig >> 3;
  const int gm = xcd & 3, gn = xcd >> 2;
  const int m0 = (gm * 16 + (idx & 15)) * 128;
  const int n0 = (gn * 4 + (idx >> 4)) * 128;
  const int tid = threadIdx.x;
  const int lane = tid & 63, wid = tid >> 6;
  const int wr = wid >> 1, wc = wid & 1;
  const int lr = lane & 15, lg = lane >> 4;

  f32x4 acc[4][4] = {};

  const unsigned short* gA = A + (size_t)m0 * K;
  const unsigned short* gW = W + (size_t)n0 * K;

  for (int kt = 0; kt < K; kt += 64) {
#pragma unroll
    for (int i = 0; i < 4; ++i) {
      int c = tid + i * 256;
      int row = c >> 3, col = (c & 7) << 3;
      GLDS(gA + (size_t)row * K + kt + col, (char*)sA + (size_t)c * 16);
      GLDS(gW + (size_t)row * K + kt + col, (char*)sB + (size_t)c * 16);
    }
    __syncthreads();
#pragma unroll
    for (int kk = 0; kk < 64; kk += 32) {
      bf16x8 a[4], b[4];
      const int co = kk + lg * 8;
#pragma unroll
      for (int m = 0; m < 4; ++m)
        a[m] = *reinterpret_cast<const bf16x8*>(sA + (wr * 64 + m * 16 + lr) * 64 + co);
#pragma unroll
      for (int n = 0; n < 4; ++n)
        b[n] = *reinterpret_cast<const bf16x8*>(sB + (wc * 64 + n * 16 + lr) * 64 + co);
      __builtin_amdgcn_s_setprio(1);
#pragma unroll
      for (int m = 0; m < 4; ++m)
#pragma unroll
        for (int n = 0; n < 4; ++n)
          acc[m][n] = mfma16(a[m], b[n], acc[m][n]);
      __builtin_amdgcn_s_setprio(0);
    }
    __syncthreads();
  }

#pragma unroll
  for (int m = 0; m < 4; ++m) {
    int row0 = m0 + wr * 64 + m * 16 + lg * 4;
#pragma unroll
    for (int n = 0; n < 4; ++n) {
      int col = n0 + wc * 64 + n * 16 + lr;
      float bvv = bias[col];
#pragma unroll
      for (int r = 0; r < 4; ++r)
        C[(size_t)(row0 + r) * HID + col] = acc[m][n][r] + bvv;
    }
  }
}

// ---------------- attention: 32x32 MFMA, in-register softmax (r18) ----------------
// grid (bh=64, qt=16); 4 waves; wave owns 32 q-rows (band wid*32..+31).
// Per 64-kv tile: GLDS K,V -> barrier -> S -> exp/pack -> PV -> barrier.
// S^T: lane(q=l31,hi): kv = nblk*32 + (reg&3)+8*(reg>>2)+4*hi.
// exp+pack: single asm block (16 v_exp, s_nop, 8 cvt_pk). V kv-permuted ->
// PV B-frag one b128 read. den via mfma(P, ones).
#define KVB 64

__global__ __launch_bounds__(256, 4) void k_attn(
    const unsigned short* __restrict__ Qg,  // [64][2048][64]
    const unsigned short* __restrict__ Kg,  // [64][2048][64]
    const unsigned short* __restrict__ Vt,  // [64][64][2048] kv-permuted
    unsigned short* __restrict__ Og) {      // [8192][1024] bf16
  __shared__ __align__(16) unsigned short smem[128 * 64]; // 16KB

  const int bh = blockIdx.x;
  const int qt = blockIdx.y;
  const int tid = threadIdx.x;
  const int lane = tid & 63, wid = tid >> 6;
  const int l31 = lane & 31, hi = lane >> 5;

  const unsigned short* Kh = Kg + (size_t)bh * SEQ * HD;
  const unsigned short* Vh = Vt + (size_t)bh * HD * SEQ;

  char* sK = (char*)smem;           // [64 kv][128B]
  char* sV = (char*)smem + 8192;    // [64 d ][128B] (kv-permuted cols)

  // staging geometry: chunks c0=tid (row r0 in 0..31), c1=tid+256 (row r0+32)
  const int r0 = tid >> 3, r1 = r0 + 32;
  const int cb0 = SWZ(r0, (tid & 7) << 4) >> 1; // pre-swizzled source short-offset
  const int cb1 = SWZ(r1, (tid & 7) << 4) >> 1;

  // Q B-frags straight from global: row q = wid*32+l31, d = ks*16 + hi*8 + j
  bf16x8 qb[4];
  {
    const unsigned short* Qrow =
        Qg + ((size_t)bh * SEQ + (size_t)qt * 128 + wid * 32 + l31) * HD;
#pragma unroll
    for (int ks = 0; ks < 4; ++ks)
      qb[ks] = *reinterpret_cast<const bf16x8*>(Qrow + ks * 16 + hi * 8);
  }

  const unsigned short onev = (unsigned short)0x3F80; // bf16 1.0
  const bf16x8 ones = {(short)onev, (short)onev, (short)onev, (short)onev,
                       (short)onev, (short)onev, (short)onev, (short)onev};

  f32x16 acco[2] = {};  // O: col d = dblk*32+l31, row q = crow(reg,hi)
  f32x16 accd = {};     // den, same layout

  for (int kt = 0; kt < SEQ; kt += KVB) {
    // stage K [64 kv][64 d] and V^T [64 d][64 kv] (pre-swizzled source)
    GLDS(Kh + (size_t)(kt + r0) * HD + cb0, sK + (size_t)tid * 16);
    GLDS(Kh + (size_t)(kt + r1) * HD + cb1, sK + (size_t)(tid + 256) * 16);
    GLDS(Vh + (size_t)r0 * SEQ + kt + cb0, sV + (size_t)tid * 16);
    GLDS(Vh + (size_t)r1 * SEQ + kt + cb1, sV + (size_t)(tid + 256) * 16);
    __syncthreads(); // staged tiles visible (vmcnt drained)

    // S^T: accs[nblk], kv = nblk*32 + crow(reg,hi), q = l31
    f32x16 accs[2] = {};
#pragma unroll
    for (int ks = 0; ks < 4; ++ks) {
      bf16x8 ka0 = *reinterpret_cast<const bf16x8*>(
          sK + (0 + l31) * 128 + SWZ(l31, ks * 32 + hi * 16));
      bf16x8 ka1 = *reinterpret_cast<const bf16x8*>(
          sK + (32 + l31) * 128 + SWZ(32 + l31, ks * 32 + hi * 16));
      __builtin_amdgcn_s_setprio(1);
      accs[0] = mfma32(ka0, qb[ks], accs[0]);
      accs[1] = mfma32(ka1, qb[ks], accs[1]);
      __builtin_amdgcn_s_setprio(0);
    }

    // P = 2^(S*log2e/32): ONE asm block per 16 values — 16 v_exp then 8
    // cvt_pk, >=8-instr TRANS->VALU spacing by construction.
    bf16x8 pa[4];
#pragma unroll
    for (int nblk = 0; nblk < 2; ++nblk) {
      float p0 = accs[nblk][0],  p1 = accs[nblk][1],  p2 = accs[nblk][2],  p3 = accs[nblk][3];
      float p4 = accs[nblk][4],  p5 = accs[nblk][5],  p6 = accs[nblk][6],  p7 = accs[nblk][7];
      float p8 = accs[nblk][8],  p9 = accs[nblk][9],  p10 = accs[nblk][10], p11 = accs[nblk][11];
      float p12 = accs[nblk][12], p13 = accs[nblk][13], p14 = accs[nblk][14], p15 = accs[nblk][15];
      unsigned w0, w1, w2, w3, w4, w5, w6, w7;
      asm("v_exp_f32 %8, %8\n\t"
          "v_exp_f32 %9, %9\n\t"
          "v_exp_f32 %10, %10\n\t"
          "v_exp_f32 %11, %11\n\t"
          "v_exp_f32 %12, %12\n\t"
          "v_exp_f32 %13, %13\n\t"
          "v_exp_f32 %14, %14\n\t"
          "v_exp_f32 %15, %15\n\t"
          "v_exp_f32 %16, %16\n\t"
          "v_exp_f32 %17, %17\n\t"
          "v_exp_f32 %18, %18\n\t"
          "v_exp_f32 %19, %19\n\t"
          "v_exp_f32 %20, %20\n\t"
          "v_exp_f32 %21, %21\n\t"
          "v_exp_f32 %22, %22\n\t"
          "v_exp_f32 %23, %23\n\t"
          "s_nop 3\n\t"
          "v_cvt_pk_bf16_f32 %0, %8, %9\n\t"
          "v_cvt_pk_bf16_f32 %1, %10, %11\n\t"
          "v_cvt_pk_bf16_f32 %2, %12, %13\n\t"
          "v_cvt_pk_bf16_f32 %3, %14, %15\n\t"
          "v_cvt_pk_bf16_f32 %4, %16, %17\n\t"
          "v_cvt_pk_bf16_f32 %5, %18, %19\n\t"
          "v_cvt_pk_bf16_f32 %6, %20, %21\n\t"
          "v_cvt_pk_bf16_f32 %7, %22, %23"
          : "=&v"(w0), "=&v"(w1), "=&v"(w2), "=&v"(w3),
            "=&v"(w4), "=&v"(w5), "=&v"(w6), "=&v"(w7),
            "+v"(p0), "+v"(p1), "+v"(p2), "+v"(p3),
            "+v"(p4), "+v"(p5), "+v"(p6), "+v"(p7),
            "+v"(p8), "+v"(p9), "+v"(p10), "+v"(p11),
            "+v"(p12), "+v"(p13), "+v"(p14), "+v"(p15));
      uint4 lo4; lo4.x = w0; lo4.y = w1; lo4.z = w2; lo4.w = w3;
      uint4 hi4; hi4.x = w4; hi4.y = w5; hi4.z = w6; hi4.w = w7;
      pa[nblk * 2 + 0] = *reinterpret_cast<bf16x8*>(&lo4);
      pa[nblk * 2 + 1] = *reinterpret_cast<bf16x8*>(&hi4);
    }

    // PV: O += P V ; den += P * ones. Instance i covers kv window i*16..+15;
    // V global layout is kv-permuted so the B-frag is one b128 read.
#pragma unroll
    for (int i = 0; i < 4; ++i) {
      bf16x8 vb[2];
#pragma unroll
      for (int dblk = 0; dblk < 2; ++dblk) {
        const int rsw = dblk * 32 + l31;
        vb[dblk] = *reinterpret_cast<const bf16x8*>(
            sV + rsw * 128 + SWZ(rsw, i * 32 + hi * 16));
      }
      __builtin_amdgcn_s_setprio(1);
      acco[0] = mfma32(pa[i], vb[0], acco[0]);
      acco[1] = mfma32(pa[i], vb[1], acco[1]);
      accd = mfma32(pa[i], ones, accd);
      __builtin_amdgcn_s_setprio(0);
    }

    __syncthreads(); // protect sK/sV before next tile's staging
  }

  // epilogue: O[q][d] = acco/accd; q = crow(reg,hi), d = dblk*32 + l31
  const int b = bh >> 4, h = bh & 15;
#pragma unroll
  for (int reg = 0; reg < 16; ++reg) {
    int q = (reg & 3) + 8 * (reg >> 2) + 4 * hi;
    int tok = qt * 128 + wid * 32 + q;
    float rd = 1.0f / accd[reg];
    size_t rowoff = (size_t)(b * SEQ + tok) * HID + h * 64;
    Og[rowoff + l31] = f2bf(acco[0][reg] * rd);
    Og[rowoff + 32 + l31] = f2bf(acco[1][reg] * rd);
  }
}

// ---------------- launch ----------------
extern "C" void kernel_launch(void* const* d_in, const int* in_sizes, int n_in,
                              void* d_out, int out_size, void* d_ws, size_t ws_size,
                              hipStream_t stream) {
  (void)in_sizes; (void)n_in; (void)out_size; (void)ws_size;
  const float* x = (const float*)d_in[0];
  const float* Wq = (const float*)d_in[1];
  const float* bq = (const float*)d_in[2];
  const float* Wk = (const float*)d_in[3];
  const float* bk = (const float*)d_in[4];
  const float* Wv = (const float*)d_in[5];
  const float* bv = (const float*)d_in[6];
  const float* Wo = (const float*)d_in[7];
  const float* bo = (const float*)d_in[8];

  unsigned short* ws = (unsigned short*)d_ws;
  unsigned short* xb = ws;
  unsigned short* wqb = xb + (size_t)MTOT * HID;  // Wq;Wk;Wv;Wo contiguous
  unsigned short* wob = wqb + 3 * (size_t)HID * HID;
  unsigned short* qb = wob + (size_t)HID * HID;   // [64][2048][64]
  unsigned short* kb = qb + (size_t)MTOT * HID;   // [64][2048][64]
  unsigned short* vtb = kb + (size_t)MTOT * HID;  // [64][64][2048] kv-permuted
  unsigned short* ob = vtb + (size_t)MTOT * HID;  // [8192][1024]

  const float cexp = 0.04508422f; // log2(e)/32 — attn computes 2^(S*cexp)

  k_cvt_all<<<(MTOT * HID / 4 + 4 * (HID * HID / 4)) / 256, 256, 0, stream>>>(
      x, Wq, Wk, Wv, Wo, ws);

  k_gemm3<<<dim3(64, 24), 256, 0, stream>>>(
      xb, wqb, bq, bk, bv, qb, kb, vtb, cexp);

  k_attn<<<dim3(64, SEQ / 128), 256, 0, stream>>>(qb, kb, vtb, ob);

  k_gemmo<<<dim3(64, 8), 256, 0, stream>>>(ob, wob, bo, (float*)d_out);
}